// Round 1
// 1619.155 us; speedup vs baseline: 1.0387x; 1.0387x over previous
//
#include <hip/hip_runtime.h>
#include <hip/hip_bf16.h>

// LLaMA layer, MI355X. Round 3: pipelined double-buffered GEMM + split-K.
// rmsnorm -> Q GEMM (split-K 2) -> combine+rope (table) -> attn_flash (MFMA)
// -> O GEMM (split-K 2) -> combine -> rmsnorm -> w1/w3 GEMMs -> silu-mul
// -> w2 GEMM (split-K 2) -> combine.
// GEMM: C[M,N] = A[M,K](bf16) @ W[N,K]^T(fp32 -> bf16 in reg staging).
// 128x128 tile, BK=64, 2-phase pipeline: A via global_load_lds (swizzled
// source + swizzled ds_read, rule 21), W via early-issued float4 loads ->
// cvt -> ds_write_b128; one __syncthreads per K-step (its vmcnt(0) drain
// sits AFTER the 32-MFMA compute phase, hiding load latency).

typedef __attribute__((ext_vector_type(4))) float  floatx4;
typedef __attribute__((ext_vector_type(8))) __bf16 bf16x8;
typedef __attribute__((ext_vector_type(4))) __bf16 bf16x4;

#define HIDDEN 4096
#define FFN    11008
#define SEQLEN 1024
#define NHEADS 32
#define HDIM   128
#define PAST   1024

__device__ __forceinline__ void gload_lds16(const void* g, void* l) {
    __builtin_amdgcn_global_load_lds(
        (const __attribute__((address_space(1))) void*)g,
        (__attribute__((address_space(3))) void*)l, 16, 0, 0);
}

// ---------------- rmsnorm (fp32 in -> bf16 out), one block per row ----------
__global__ __launch_bounds__(256) void rmsnorm_bf16(
    const float* __restrict__ x, const float* __restrict__ w,
    __bf16* __restrict__ out)
{
    const int row = blockIdx.x;
    const float* xr = x + (size_t)row * HIDDEN;
    float4 v[4];
    float ss = 0.f;
#pragma unroll
    for (int i = 0; i < 4; ++i) {
        v[i] = *(const float4*)(xr + threadIdx.x * 4 + i * 1024);
        ss += v[i].x * v[i].x + v[i].y * v[i].y + v[i].z * v[i].z + v[i].w * v[i].w;
    }
#pragma unroll
    for (int off = 32; off > 0; off >>= 1) ss += __shfl_down(ss, off);
    __shared__ float red[4];
    if ((threadIdx.x & 63) == 0) red[threadIdx.x >> 6] = ss;
    __syncthreads();
    float total = red[0] + red[1] + red[2] + red[3];
    float scale = rsqrtf(total * (1.f / HIDDEN) + 1e-6f);
#pragma unroll
    for (int i = 0; i < 4; ++i) {
        int idx = threadIdx.x * 4 + i * 1024;
        float4 wv = *(const float4*)(w + idx);
        bf16x4 o;
        o[0] = (__bf16)(v[i].x * scale * wv.x);
        o[1] = (__bf16)(v[i].y * scale * wv.y);
        o[2] = (__bf16)(v[i].z * scale * wv.z);
        o[3] = (__bf16)(v[i].w * scale * wv.w);
        *(bf16x4*)(out + (size_t)row * HIDDEN + idx) = o;
    }
}

// ---------------- pipelined GEMM -------------------------------------------
// C[M,N](fp32) = A[M,K](bf16) @ W[N,K]^T(fp32). SPLIT>1: partials at
// C + z*M*N over K/SPLIT chunks. 256 threads, 4 waves, 4x4 frags/wave.
template<int SPLIT>
__global__ __launch_bounds__(256, 2) void gemm2(
    const __bf16* __restrict__ A, const float* __restrict__ W,
    float* __restrict__ C, int M, int N, int K)
{
    __shared__ __bf16 Asb[2][128 * 64];   // linear (gload_lds dest), XOR-swizzled content
    __shared__ __bf16 Bsb[2][128 * 72];   // padded stride 72 (144B rows)

    const int tid  = threadIdx.x;
    const int wave = tid >> 6;
    const int lane = tid & 63;
    const int l15  = lane & 15;
    const int quad = lane >> 4;
    const int wr   = wave >> 1;
    const int wc   = wave & 1;

    // XCD-bijective swizzle (m204), M-fastest so same-W blocks share an L2
    const int nwg = gridDim.x;
    int flat = blockIdx.x;
    int q = nwg >> 3, r = nwg & 7;
    int xcd = flat & 7, ii = flat >> 3;
    int nf = (xcd < r) ? (xcd * (q + 1) + ii) : (r * (q + 1) + (xcd - r) * q + ii);
    const int gm = M >> 7;
    const int bn = nf / gm, bm = nf - bn * gm;

    const int Kper  = K / SPLIT;
    const int kbase = blockIdx.y * Kper;
    const int nt    = Kper >> 6;

    // A staging: chunk c = wave*4+i covers rows c*8..c*8+7; lane l handles
    // row c*8+(l>>3), within-row byte (l&7)*16, holding GLOBAL kbyte
    // ((l&7)*16) ^ ((l>>3)<<4)  (both-sides swizzle: pre-swizzled source).
    const int arow = (lane >> 3);
    const int akb  = ((lane & 7) * 16) ^ ((lane >> 3) << 4);
    const __bf16* Abase = A + (size_t)(bm * 128) * K + kbase + (akb >> 1);

    // W staging: thread -> row tid>>1, k-half (tid&1)*32, 8x float4
    const int wrow = tid >> 1, wh = tid & 1;
    const float* Wbase = W + (size_t)(bn * 128 + wrow) * K + kbase + wh * 32;

    floatx4 acc[4][4] = {};
    float4 wreg[8];

    // ---- prologue: tile 0 into buf 0 ----
    {
#pragma unroll
        for (int j = 0; j < 8; ++j)
            wreg[j] = *(const float4*)(Wbase + j * 4);
#pragma unroll
        for (int i = 0; i < 4; ++i) {
            int c = wave * 4 + i;
            gload_lds16(Abase + (size_t)(c * 8 + arow) * K, &Asb[0][c * 512]);
        }
#pragma unroll
        for (int j = 0; j < 4; ++j) {
            bf16x8 b;
            b[0] = (__bf16)wreg[2*j].x;   b[1] = (__bf16)wreg[2*j].y;
            b[2] = (__bf16)wreg[2*j].z;   b[3] = (__bf16)wreg[2*j].w;
            b[4] = (__bf16)wreg[2*j+1].x; b[5] = (__bf16)wreg[2*j+1].y;
            b[6] = (__bf16)wreg[2*j+1].z; b[7] = (__bf16)wreg[2*j+1].w;
            *(bf16x8*)(&Bsb[0][wrow * 72 + wh * 32 + j * 8]) = b;
        }
        __syncthreads();   // vmcnt(0) lgkmcnt(0) barrier: tile 0 ready
    }

    for (int t = 0; t < nt; ++t) {
        const int cur = t & 1, nxt = cur ^ 1;
        const bool more = (t + 1 < nt);

        // issue next tile's loads BEFORE compute (latency hides under MFMA)
        if (more) {
            const float* wb = Wbase + (t + 1) * 64;
#pragma unroll
            for (int j = 0; j < 8; ++j)
                wreg[j] = *(const float4*)(wb + j * 4);
            const __bf16* ab = Abase + (t + 1) * 64;
#pragma unroll
            for (int i = 0; i < 4; ++i) {
                int c = wave * 4 + i;
                gload_lds16(ab + (size_t)(c * 8 + arow) * K, &Asb[nxt][c * 512]);
            }
        }

        // compute tile t (32 MFMA / wave)
#pragma unroll
        for (int kk = 0; kk < 2; ++kk) {
            bf16x8 af[4], bfr[4];
#pragma unroll
            for (int i = 0; i < 4; ++i) {
                int R  = wr * 64 + i * 16 + l15;
                int kb = (kk * 64 + quad * 16) ^ ((l15 & 7) << 4);
                af[i] = *(const bf16x8*)((const char*)&Asb[cur][R * 64] + kb);
            }
#pragma unroll
            for (int j = 0; j < 4; ++j) {
                int R2 = wc * 64 + j * 16 + l15;
                bfr[j] = *(const bf16x8*)(&Bsb[cur][R2 * 72 + kk * 32 + quad * 8]);
            }
#pragma unroll
            for (int i = 0; i < 4; ++i)
#pragma unroll
                for (int j = 0; j < 4; ++j)
                    acc[i][j] = __builtin_amdgcn_mfma_f32_16x16x32_bf16(af[i], bfr[j], acc[i][j], 0, 0, 0);
        }

        if (more) {
            // W(t+1): cvt + ds_write (compiler waits its vmcnt here, post-MFMA)
#pragma unroll
            for (int j = 0; j < 4; ++j) {
                bf16x8 b;
                b[0] = (__bf16)wreg[2*j].x;   b[1] = (__bf16)wreg[2*j].y;
                b[2] = (__bf16)wreg[2*j].z;   b[3] = (__bf16)wreg[2*j].w;
                b[4] = (__bf16)wreg[2*j+1].x; b[5] = (__bf16)wreg[2*j+1].y;
                b[6] = (__bf16)wreg[2*j+1].z; b[7] = (__bf16)wreg[2*j+1].w;
                *(bf16x8*)(&Bsb[nxt][wrow * 72 + wh * 32 + j * 8]) = b;
            }
            __syncthreads();   // drains gload_lds A(t+1) + orders Bsb writes
        }
    }

    // epilogue: D row = quad*4+reg, col = lane&15
    float* Co = (SPLIT > 1) ? (C + (size_t)blockIdx.y * M * N) : C;
#pragma unroll
    for (int i = 0; i < 4; ++i) {
        int mrow = bm * 128 + wr * 64 + i * 16 + quad * 4;
#pragma unroll
        for (int j = 0; j < 4; ++j) {
            int ncol = bn * 128 + wc * 64 + j * 16 + l15;
            float* cp = Co + (size_t)mrow * N + ncol;
#pragma unroll
            for (int rr = 0; rr < 4; ++rr)
                cp[(size_t)rr * N] = acc[i][j][rr];
        }
    }
}

// ---------------- rope table: [s][j] -> (cos, sin) --------------------------
__global__ __launch_bounds__(256) void rope_table(float* __restrict__ tab)
{
    int idx = blockIdx.x * 256 + threadIdx.x;   // 1024*64
    int s = idx >> 6, j = idx & 63;
    float freq = __powf(10000.f, -(float)(2 * j) * (1.f / 128.f));
    float sn, cs;
    __sincosf((float)s * freq, &sn, &cs);
    tab[2 * idx]     = cs;
    tab[2 * idx + 1] = sn;
}

// ---------------- split-K combine + rope + cast (Q path) --------------------
__global__ __launch_bounds__(256) void combine_rope(
    const float* __restrict__ p, const float* __restrict__ tab,
    __bf16* __restrict__ out)
{
    const int s = blockIdx.x;
    const float* r0 = p + (size_t)s * HIDDEN;
    const float* r1 = r0 + (size_t)SEQLEN * HIDDEN;
    __bf16* orow = out + (size_t)s * HIDDEN;
    for (int pi = threadIdx.x; pi < 2048; pi += 256) {
        int h = pi >> 6, j = pi & 63;
        int base = h * 128;
        float2 e0 = *(const float2*)(r0 + base + 2 * j);
        float2 e1 = *(const float2*)(r1 + base + 2 * j);
        float xe = e0.x + e1.x, xo = e0.y + e1.y;
        float2 cs = *(const float2*)(tab + (size_t)s * 128 + 2 * j);
        orow[base + j]      = (__bf16)(xe * cs.x - xo * cs.y);
        orow[base + 64 + j] = (__bf16)(xe * cs.y + xo * cs.x);
    }
}

// ---------------- split-K combine (fp32 add) --------------------------------
__global__ __launch_bounds__(256) void combine_add(
    const float* __restrict__ p, float* __restrict__ out, int n)
{
    int i = (blockIdx.x * 256 + threadIdx.x) * 4;
    float4 a = *(const float4*)(p + i);
    float4 b = *(const float4*)(p + n + i);
    float4 o; o.x = a.x + b.x; o.y = a.y + b.y; o.z = a.z + b.z; o.w = a.w + b.w;
    *(float4*)(out + i) = o;
}

// ---------------- flash attention (MFMA) — unchanged this round -------------
__global__ __launch_bounds__(256) void attn_flash(
    const __bf16* __restrict__ q, const float* __restrict__ pk,
    const float* __restrict__ pv, __bf16* __restrict__ out)
{
    const int qt = blockIdx.x;
    const int h  = blockIdx.y;
    const int s0 = qt * 64;
    const int tid  = threadIdx.x;
    const int wave = tid >> 6;
    const int lane = tid & 63;
    const int l15  = lane & 15;
    const int quad = lane >> 4;

    __shared__ __bf16 Ks[64 * 136];
    __shared__ __bf16 Vt[128 * 72];
    __shared__ __bf16 Ps[64 * 72];

    bf16x8 qf[4];
    {
        const __bf16* qrow = q + (size_t)(s0 + wave * 16 + l15) * HIDDEN + h * HDIM;
#pragma unroll
        for (int ks = 0; ks < 4; ++ks)
            qf[ks] = *(const bf16x8*)(qrow + ks * 32 + quad * 8);
    }

    floatx4 Oa[8] = {};
    float m_r[4], l_r[4];
#pragma unroll
    for (int r = 0; r < 4; ++r) { m_r[r] = -1e30f; l_r[r] = 0.f; }

    for (int p0 = 0; p0 < PAST; p0 += 64) {
        const float* kbase = pk + ((size_t)h * PAST + p0) * HDIM;
        const float* vbase = pv + ((size_t)h * PAST + p0) * HDIM;
#pragma unroll
        for (int i = 0; i < 8; ++i) {
            int f = i * 256 + tid;
            int p = f >> 5, dq = (f & 31) * 4;
            float4 k4 = *(const float4*)(kbase + p * HDIM + dq);
            bf16x4 kb;
            kb[0] = (__bf16)k4.x; kb[1] = (__bf16)k4.y;
            kb[2] = (__bf16)k4.z; kb[3] = (__bf16)k4.w;
            *(bf16x4*)(&Ks[p * 136 + dq]) = kb;
            float4 v4 = *(const float4*)(vbase + p * HDIM + dq);
            Vt[(dq + 0) * 72 + p] = (__bf16)v4.x;
            Vt[(dq + 1) * 72 + p] = (__bf16)v4.y;
            Vt[(dq + 2) * 72 + p] = (__bf16)v4.z;
            Vt[(dq + 3) * 72 + p] = (__bf16)v4.w;
        }
        __syncthreads();

        floatx4 Sa[4] = {};
#pragma unroll
        for (int nb = 0; nb < 4; ++nb)
#pragma unroll
            for (int ks = 0; ks < 4; ++ks) {
                bf16x8 kf = *(const bf16x8*)(&Ks[(nb * 16 + l15) * 136 + ks * 32 + quad * 8]);
                Sa[nb] = __builtin_amdgcn_mfma_f32_16x16x32_bf16(qf[ks], kf, Sa[nb], 0, 0, 0);
            }

        float mnew[4];
#pragma unroll
        for (int r = 0; r < 4; ++r) {
            float t = fmaxf(fmaxf(Sa[0][r], Sa[1][r]), fmaxf(Sa[2][r], Sa[3][r]));
#pragma unroll
            for (int off = 1; off < 16; off <<= 1) t = fmaxf(t, __shfl_xor(t, off));
            mnew[r] = fmaxf(m_r[r], t);
        }
#pragma unroll
        for (int r = 0; r < 4; ++r) {
            float alpha = __expf(m_r[r] - mnew[r]);
            m_r[r] = mnew[r];
            float s = 0.f;
#pragma unroll
            for (int nb = 0; nb < 4; ++nb) {
                float e = __expf(Sa[nb][r] - mnew[r]);
                Sa[nb][r] = e;
                s += e;
            }
#pragma unroll
            for (int off = 1; off < 16; off <<= 1) s += __shfl_xor(s, off);
            l_r[r] = l_r[r] * alpha + s;
#pragma unroll
            for (int nb = 0; nb < 8; ++nb) Oa[nb][r] *= alpha;
        }

#pragma unroll
        for (int nb = 0; nb < 4; ++nb)
#pragma unroll
            for (int r = 0; r < 4; ++r)
                Ps[(wave * 16 + quad * 4 + r) * 72 + nb * 16 + l15] = (__bf16)Sa[nb][r];

#pragma unroll
        for (int ks2 = 0; ks2 < 2; ++ks2) {
            bf16x8 pf = *(const bf16x8*)(&Ps[(wave * 16 + l15) * 72 + ks2 * 32 + quad * 8]);
#pragma unroll
            for (int nb = 0; nb < 8; ++nb) {
                bf16x8 vf = *(const bf16x8*)(&Vt[(nb * 16 + l15) * 72 + ks2 * 32 + quad * 8]);
                Oa[nb] = __builtin_amdgcn_mfma_f32_16x16x32_bf16(pf, vf, Oa[nb], 0, 0, 0);
            }
        }
        __syncthreads();
    }

    float inv[4];
#pragma unroll
    for (int r = 0; r < 4; ++r) inv[r] = 1.f / l_r[r];
#pragma unroll
    for (int nb = 0; nb < 8; ++nb)
#pragma unroll
        for (int r = 0; r < 4; ++r)
            out[(size_t)(s0 + wave * 16 + quad * 4 + r) * HIDDEN + h * HDIM + nb * 16 + l15] =
                (__bf16)(Oa[nb][r] * inv[r]);
}

// ---------------- elementwise ------------------------------------------
__global__ __launch_bounds__(256) void silu_mul_bf16(
    const float* __restrict__ x1, const float* __restrict__ x3,
    __bf16* __restrict__ out)
{
    int i = (blockIdx.x * 256 + threadIdx.x) * 4;
    float4 a = *(const float4*)(x1 + i);
    float4 b = *(const float4*)(x3 + i);
    bf16x4 o;
    o[0] = (__bf16)(a.x * (b.x / (1.f + __expf(-b.x))));
    o[1] = (__bf16)(a.y * (b.y / (1.f + __expf(-b.y))));
    o[2] = (__bf16)(a.z * (b.z / (1.f + __expf(-b.z))));
    o[3] = (__bf16)(a.w * (b.w / (1.f + __expf(-b.w))));
    *(bf16x4*)(out + i) = o;
}

// ---------------- launch -------------------------------------------------
extern "C" void kernel_launch(void* const* d_in, const int* in_sizes, int n_in,
                              void* d_out, int out_size, void* d_ws, size_t ws_size,
                              hipStream_t stream)
{
    const float* x   = (const float*)d_in[0];
    const float* wq  = (const float*)d_in[1];
    // d_in[2]=wk, d_in[3]=wv: structurally dead (attention uses only past_k/v)
    const float* wo  = (const float*)d_in[4];
    const float* w1  = (const float*)d_in[5];
    const float* w2  = (const float*)d_in[6];
    const float* w3  = (const float*)d_in[7];
    const float* anw = (const float*)d_in[8];
    const float* fnw = (const float*)d_in[9];
    const float* pk  = (const float*)d_in[10];
    const float* pv  = (const float*)d_in[11];
    float* out = (float*)d_out;

    // Workspace (aliased by live range; peak ~124 MB):
    //  [0,0.5) tab | [0.5,8.5) h_bf -> xq_bf -> (xo head) -> (x1 head) -> w2p
    //  [8.5,40.5) qp ; ao_bf at [8.5,16.5) after qp dies
    //  [16.5,48.5) op | xo [0.5,16.5) | hf [48.5,56.5) | x1 [0.5,45.6)
    //  x3 [56.5,101.6) | g_bf [102.5,124.5) | w2p [0.5,32.5)
    char* ws = (char*)d_ws;
    constexpr size_t MB  = 1ull << 20;
    constexpr size_t HMB = 512ull << 10;
    float*  tab   = (float*)(ws);                   // 0.5 MB
    __bf16* h_bf  = (__bf16*)(ws + HMB);            // 8 MB
    float*  qp    = (float*)(ws + HMB + 8  * MB);   // 32 MB (2 partials)
    __bf16* xq_bf = (__bf16*)(ws + HMB);            // alias h_bf (dead)
    __bf16* ao_bf = (__bf16*)(ws + HMB + 8  * MB);  // alias qp head (dead)
    float*  op    = (float*)(ws + HMB + 16 * MB);   // 32 MB (2 partials)
    float*  xo    = (float*)(ws + HMB);             // 16 MB (xq/ao dead)
    __bf16* hf_bf = (__bf16*)(ws + HMB + 48 * MB);  // 8 MB
    float*  x1    = (float*)(ws + HMB);             // 45.1 MB (xo dead)
    float*  x3    = (float*)(ws + HMB + 56 * MB);   // 45.1 MB
    __bf16* g_bf  = (__bf16*)(ws + HMB + 102 * MB); // 22.5 MB
    float*  w2p   = (float*)(ws + HMB);             // 32 MB (x1 dead)

    rope_table<<<256, 256, 0, stream>>>(tab);
    rmsnorm_bf16<<<SEQLEN, 256, 0, stream>>>(x, anw, h_bf);
    gemm2<2><<<dim3((HIDDEN / 128) * (SEQLEN / 128), 2), 256, 0, stream>>>(
        h_bf, wq, qp, SEQLEN, HIDDEN, HIDDEN);
    combine_rope<<<SEQLEN, 256, 0, stream>>>(qp, tab, xq_bf);
    attn_flash<<<dim3(SEQLEN / 64, NHEADS), 256, 0, stream>>>(xq_bf, pk, pv, ao_bf);
    gemm2<2><<<dim3((HIDDEN / 128) * (SEQLEN / 128), 2), 256, 0, stream>>>(
        ao_bf, wo, op, SEQLEN, HIDDEN, HIDDEN);
    combine_add<<<(SEQLEN * HIDDEN) / 1024, 256, 0, stream>>>(op, xo, SEQLEN * HIDDEN);
    rmsnorm_bf16<<<SEQLEN, 256, 0, stream>>>(xo, fnw, hf_bf);
    gemm2<1><<<dim3((FFN / 128) * (SEQLEN / 128), 1), 256, 0, stream>>>(
        hf_bf, w1, x1, SEQLEN, FFN, HIDDEN);
    gemm2<1><<<dim3((FFN / 128) * (SEQLEN / 128), 1), 256, 0, stream>>>(
        hf_bf, w3, x3, SEQLEN, FFN, HIDDEN);
    silu_mul_bf16<<<(SEQLEN * FFN) / 1024, 256, 0, stream>>>(x1, x3, g_bf);
    gemm2<2><<<dim3((HIDDEN / 128) * (SEQLEN / 128), 2), 256, 0, stream>>>(
        g_bf, w2, w2p, SEQLEN, HIDDEN, FFN);
    combine_add<<<(SEQLEN * HIDDEN) / 1024, 256, 0, stream>>>(w2p, out, SEQLEN * HIDDEN);
}

// Round 3
// 1377.765 us; speedup vs baseline: 1.2207x; 1.1752x over previous
//
#include <hip/hip_runtime.h>
#include <hip/hip_bf16.h>

// LLaMA layer, MI355X. Round 5 (= round 4 resubmit after infra failure):
// m97-style GEMM — both operands staged via global_load_lds (no data-register
// staging, so the allocator cannot sink the prefetch), BK=32, single LDS
// buffer (24 KB), 2 barriers/step, 4 blocks/CU via __launch_bounds__(256,4).
// W stays fp32 in LDS; fp32->bf16 conversion at fragment-read time (m240).
// Both tiles use rule-21 both-sides XOR swizzle: linear gload_lds dest,
// pre-swizzled global source, XOR-swizzled ds_read.
// Q/O/w2 GEMMs split-K x4 (grid 1024 -> 4 resident blocks/CU).

typedef __attribute__((ext_vector_type(4))) float  floatx4;
typedef __attribute__((ext_vector_type(8))) __bf16 bf16x8;
typedef __attribute__((ext_vector_type(4))) __bf16 bf16x4;

#define HIDDEN 4096
#define FFN    11008
#define SEQLEN 1024
#define NHEADS 32
#define HDIM   128
#define PAST   1024

__device__ __forceinline__ void gload_lds16(const void* g, void* l) {
    __builtin_amdgcn_global_load_lds(
        (const __attribute__((address_space(1))) void*)g,
        (__attribute__((address_space(3))) void*)l, 16, 0, 0);
}

// ---------------- rmsnorm (fp32 in -> bf16 out), one block per row ----------
__global__ __launch_bounds__(256) void rmsnorm_bf16(
    const float* __restrict__ x, const float* __restrict__ w,
    __bf16* __restrict__ out)
{
    const int row = blockIdx.x;
    const float* xr = x + (size_t)row * HIDDEN;
    float4 v[4];
    float ss = 0.f;
#pragma unroll
    for (int i = 0; i < 4; ++i) {
        v[i] = *(const float4*)(xr + threadIdx.x * 4 + i * 1024);
        ss += v[i].x * v[i].x + v[i].y * v[i].y + v[i].z * v[i].z + v[i].w * v[i].w;
    }
#pragma unroll
    for (int off = 32; off > 0; off >>= 1) ss += __shfl_down(ss, off);
    __shared__ float red[4];
    if ((threadIdx.x & 63) == 0) red[threadIdx.x >> 6] = ss;
    __syncthreads();
    float total = red[0] + red[1] + red[2] + red[3];
    float scale = rsqrtf(total * (1.f / HIDDEN) + 1e-6f);
#pragma unroll
    for (int i = 0; i < 4; ++i) {
        int idx = threadIdx.x * 4 + i * 1024;
        float4 wv = *(const float4*)(w + idx);
        bf16x4 o;
        o[0] = (__bf16)(v[i].x * scale * wv.x);
        o[1] = (__bf16)(v[i].y * scale * wv.y);
        o[2] = (__bf16)(v[i].z * scale * wv.z);
        o[3] = (__bf16)(v[i].w * scale * wv.w);
        *(bf16x4*)(out + (size_t)row * HIDDEN + idx) = o;
    }
}

// ---------------- GEMM (m97 structure) --------------------------------------
// C[M,N](fp32) = A[M,K](bf16) @ W[N,K]^T(fp32). SPLIT>1: partial z at
// C + z*M*N over K/SPLIT. 256 threads / 4 waves, 128x128 tile, BK=32.
template<int SPLIT>
__global__ __launch_bounds__(256, 4) void gemm3(
    const __bf16* __restrict__ A, const float* __restrict__ W,
    float* __restrict__ C, int M, int N, int K)
{
    __shared__ __align__(16) __bf16 As[128 * 32];   // 8 KB, 64B rows, swizzled
    __shared__ __align__(16) float  Bs[128 * 32];   // 16 KB, 128B rows, swizzled

    const int tid  = threadIdx.x;
    const int wave = tid >> 6;
    const int lane = tid & 63;
    const int l15  = lane & 15;
    const int quad = lane >> 4;
    const int wr   = wave >> 1;
    const int wc   = wave & 1;

    // XCD-bijective swizzle (m204), M-fastest: 8 M-blocks sharing a W panel
    // land on one XCD's L2.
    const int nwg = gridDim.x;
    int flat = blockIdx.x;
    int q = nwg >> 3, r = nwg & 7;
    int xcd = flat & 7, ii0 = flat >> 3;
    int nf = (xcd < r) ? (xcd * (q + 1) + ii0) : (r * (q + 1) + (xcd - r) * q + ii0);
    const int gm = M >> 7;
    const int bn = nf / gm, bm = nf - bn * gm;

    const int Kper  = K / SPLIT;
    const int kbase = (SPLIT > 1) ? blockIdx.y * Kper : 0;
    const int nt    = Kper >> 5;

    // A staging: wave w -> gload_lds insts {2w, 2w+1}; inst covers 16 rows
    // (64B each). lane l: row_in = l>>2, slot = l&3; source holds global
    // byte-in-row (slot*16) ^ ((row_in&3)<<4)  (both-sides swizzle).
    const int a_kb = ((lane & 3) * 16) ^ (((lane >> 2) & 3) << 4);
    const __bf16* Ag0 = A + (size_t)(bm * 128 + wave * 32 + (lane >> 2)) * K
                          + kbase + (a_kb >> 1);
    const __bf16* Ag1 = Ag0 + (size_t)16 * K;
    char* Al = (char*)As + wave * 2048;

    // B staging: wave w -> insts {4w..4w+3}; inst covers 8 rows (128B each).
    // lane l: row_in = l>>3, slot = l&7; source byte-in-row
    // (slot*16) ^ (row_in<<4).
    const int b_kb = ((lane & 7) * 16) ^ ((lane >> 3) << 4);
    const float* Wg = W + (size_t)(bn * 128 + wave * 32 + (lane >> 3)) * K
                        + kbase + (b_kb >> 2);
    char* Bl = (char*)Bs + wave * 4096;

    floatx4 acc[4][4] = {};

    for (int t = 0; t < nt; ++t) {
        const int ko = t * 32;
        gload_lds16(Ag0 + ko, Al);
        gload_lds16(Ag1 + ko, Al + 1024);
#pragma unroll
        for (int i = 0; i < 4; ++i)
            gload_lds16(Wg + (size_t)(8 * i) * K + ko, Bl + i * 1024);
        __syncthreads();   // vmcnt(0) drain; other resident blocks overlap

        bf16x8 af[4], bfr[4];
#pragma unroll
        for (int i = 0; i < 4; ++i) {
            int R = wr * 64 + i * 16 + l15;
            af[i] = *(const bf16x8*)((const char*)As + R * 64
                                     + ((quad * 16) ^ ((R & 3) << 4)));
        }
#pragma unroll
        for (int j = 0; j < 4; ++j) {
            int R2 = wc * 64 + j * 16 + l15;
            const char* bp = (const char*)Bs + R2 * 128;
            float4 lo = *(const float4*)(bp + ((quad * 32) ^ ((R2 & 7) << 4)));
            float4 hi = *(const float4*)(bp + ((quad * 32 + 16) ^ ((R2 & 7) << 4)));
            bf16x8 b;
            b[0] = (__bf16)lo.x; b[1] = (__bf16)lo.y;
            b[2] = (__bf16)lo.z; b[3] = (__bf16)lo.w;
            b[4] = (__bf16)hi.x; b[5] = (__bf16)hi.y;
            b[6] = (__bf16)hi.z; b[7] = (__bf16)hi.w;
            bfr[j] = b;
        }
#pragma unroll
        for (int i = 0; i < 4; ++i)
#pragma unroll
            for (int j = 0; j < 4; ++j)
                acc[i][j] = __builtin_amdgcn_mfma_f32_16x16x32_bf16(
                    af[i], bfr[j], acc[i][j], 0, 0, 0);
        __syncthreads();
    }

    float* Co = (SPLIT > 1) ? (C + (size_t)blockIdx.y * M * N) : C;
#pragma unroll
    for (int i = 0; i < 4; ++i) {
        int mrow = bm * 128 + wr * 64 + i * 16 + quad * 4;
#pragma unroll
        for (int j = 0; j < 4; ++j) {
            int ncol = bn * 128 + wc * 64 + j * 16 + l15;
            float* cp = Co + (size_t)mrow * N + ncol;
#pragma unroll
            for (int rr = 0; rr < 4; ++rr)
                cp[(size_t)rr * N] = acc[i][j][rr];
        }
    }
}

// ---------------- rope table: [s][j] -> (cos, sin) --------------------------
__global__ __launch_bounds__(256) void rope_table(float* __restrict__ tab)
{
    int idx = blockIdx.x * 256 + threadIdx.x;   // 1024*64
    int s = idx >> 6, j = idx & 63;
    float freq = __powf(10000.f, -(float)(2 * j) * (1.f / 128.f));
    float sn, cs;
    __sincosf((float)s * freq, &sn, &cs);
    tab[2 * idx]     = cs;
    tab[2 * idx + 1] = sn;
}

// ---------------- split-K(4) combine + rope + cast (Q path) -----------------
__global__ __launch_bounds__(256) void combine_rope4(
    const float* __restrict__ p, const float* __restrict__ tab,
    __bf16* __restrict__ out)
{
    const int s = blockIdx.x;
    const size_t n = (size_t)SEQLEN * HIDDEN;
    const float* r0 = p + (size_t)s * HIDDEN;
    __bf16* orow = out + (size_t)s * HIDDEN;
    for (int pi = threadIdx.x; pi < 2048; pi += 256) {
        int h = pi >> 6, j = pi & 63;
        int base = h * 128;
        float2 e0 = *(const float2*)(r0 + base + 2 * j);
        float2 e1 = *(const float2*)(r0 + n + base + 2 * j);
        float2 e2 = *(const float2*)(r0 + 2 * n + base + 2 * j);
        float2 e3 = *(const float2*)(r0 + 3 * n + base + 2 * j);
        float xe = e0.x + e1.x + e2.x + e3.x;
        float xo = e0.y + e1.y + e2.y + e3.y;
        float2 cs = *(const float2*)(tab + (size_t)s * 128 + 2 * j);
        orow[base + j]      = (__bf16)(xe * cs.x - xo * cs.y);
        orow[base + 64 + j] = (__bf16)(xe * cs.y + xo * cs.x);
    }
}

// ---------------- split-K(4) combine (fp32 add) -----------------------------
__global__ __launch_bounds__(256) void combine_add4(
    const float* __restrict__ p, float* __restrict__ out, int n)
{
    int i = (blockIdx.x * 256 + threadIdx.x) * 4;
    float4 a = *(const float4*)(p + i);
    float4 b = *(const float4*)(p + (size_t)n + i);
    float4 c = *(const float4*)(p + 2 * (size_t)n + i);
    float4 d = *(const float4*)(p + 3 * (size_t)n + i);
    float4 o;
    o.x = a.x + b.x + c.x + d.x;
    o.y = a.y + b.y + c.y + d.y;
    o.z = a.z + b.z + c.z + d.z;
    o.w = a.w + b.w + c.w + d.w;
    *(float4*)(out + i) = o;
}

// ---------------- flash attention (MFMA) — unchanged this round -------------
__global__ __launch_bounds__(256) void attn_flash(
    const __bf16* __restrict__ q, const float* __restrict__ pk,
    const float* __restrict__ pv, __bf16* __restrict__ out)
{
    const int qt = blockIdx.x;
    const int h  = blockIdx.y;
    const int s0 = qt * 64;
    const int tid  = threadIdx.x;
    const int wave = tid >> 6;
    const int lane = tid & 63;
    const int l15  = lane & 15;
    const int quad = lane >> 4;

    __shared__ __bf16 Ks[64 * 136];
    __shared__ __bf16 Vt[128 * 72];
    __shared__ __bf16 Ps[64 * 72];

    bf16x8 qf[4];
    {
        const __bf16* qrow = q + (size_t)(s0 + wave * 16 + l15) * HIDDEN + h * HDIM;
#pragma unroll
        for (int ks = 0; ks < 4; ++ks)
            qf[ks] = *(const bf16x8*)(qrow + ks * 32 + quad * 8);
    }

    floatx4 Oa[8] = {};
    float m_r[4], l_r[4];
#pragma unroll
    for (int r = 0; r < 4; ++r) { m_r[r] = -1e30f; l_r[r] = 0.f; }

    for (int p0 = 0; p0 < PAST; p0 += 64) {
        const float* kbase = pk + ((size_t)h * PAST + p0) * HDIM;
        const float* vbase = pv + ((size_t)h * PAST + p0) * HDIM;
#pragma unroll
        for (int i = 0; i < 8; ++i) {
            int f = i * 256 + tid;
            int p = f >> 5, dq = (f & 31) * 4;
            float4 k4 = *(const float4*)(kbase + p * HDIM + dq);
            bf16x4 kb;
            kb[0] = (__bf16)k4.x; kb[1] = (__bf16)k4.y;
            kb[2] = (__bf16)k4.z; kb[3] = (__bf16)k4.w;
            *(bf16x4*)(&Ks[p * 136 + dq]) = kb;
            float4 v4 = *(const float4*)(vbase + p * HDIM + dq);
            Vt[(dq + 0) * 72 + p] = (__bf16)v4.x;
            Vt[(dq + 1) * 72 + p] = (__bf16)v4.y;
            Vt[(dq + 2) * 72 + p] = (__bf16)v4.z;
            Vt[(dq + 3) * 72 + p] = (__bf16)v4.w;
        }
        __syncthreads();

        floatx4 Sa[4] = {};
#pragma unroll
        for (int nb = 0; nb < 4; ++nb)
#pragma unroll
            for (int ks = 0; ks < 4; ++ks) {
                bf16x8 kf = *(const bf16x8*)(&Ks[(nb * 16 + l15) * 136 + ks * 32 + quad * 8]);
                Sa[nb] = __builtin_amdgcn_mfma_f32_16x16x32_bf16(qf[ks], kf, Sa[nb], 0, 0, 0);
            }

        float mnew[4];
#pragma unroll
        for (int r = 0; r < 4; ++r) {
            float t = fmaxf(fmaxf(Sa[0][r], Sa[1][r]), fmaxf(Sa[2][r], Sa[3][r]));
#pragma unroll
            for (int off = 1; off < 16; off <<= 1) t = fmaxf(t, __shfl_xor(t, off));
            mnew[r] = fmaxf(m_r[r], t);
        }
#pragma unroll
        for (int r = 0; r < 4; ++r) {
            float alpha = __expf(m_r[r] - mnew[r]);
            m_r[r] = mnew[r];
            float s = 0.f;
#pragma unroll
            for (int nb = 0; nb < 4; ++nb) {
                float e = __expf(Sa[nb][r] - mnew[r]);
                Sa[nb][r] = e;
                s += e;
            }
#pragma unroll
            for (int off = 1; off < 16; off <<= 1) s += __shfl_xor(s, off);
            l_r[r] = l_r[r] * alpha + s;
#pragma unroll
            for (int nb = 0; nb < 8; ++nb) Oa[nb][r] *= alpha;
        }

#pragma unroll
        for (int nb = 0; nb < 4; ++nb)
#pragma unroll
            for (int r = 0; r < 4; ++r)
                Ps[(wave * 16 + quad * 4 + r) * 72 + nb * 16 + l15] = (__bf16)Sa[nb][r];

#pragma unroll
        for (int ks2 = 0; ks2 < 2; ++ks2) {
            bf16x8 pf = *(const bf16x8*)(&Ps[(wave * 16 + l15) * 72 + ks2 * 32 + quad * 8]);
#pragma unroll
            for (int nb = 0; nb < 8; ++nb) {
                bf16x8 vf = *(const bf16x8*)(&Vt[(nb * 16 + l15) * 72 + ks2 * 32 + quad * 8]);
                Oa[nb] = __builtin_amdgcn_mfma_f32_16x16x32_bf16(pf, vf, Oa[nb], 0, 0, 0);
            }
        }
        __syncthreads();
    }

    float inv[4];
#pragma unroll
    for (int r = 0; r < 4; ++r) inv[r] = 1.f / l_r[r];
#pragma unroll
    for (int nb = 0; nb < 8; ++nb)
#pragma unroll
        for (int r = 0; r < 4; ++r)
            out[(size_t)(s0 + wave * 16 + quad * 4 + r) * HIDDEN + h * HDIM + nb * 16 + l15] =
                (__bf16)(Oa[nb][r] * inv[r]);
}

// ---------------- elementwise ------------------------------------------
__global__ __launch_bounds__(256) void silu_mul_bf16(
    const float* __restrict__ x1, const float* __restrict__ x3,
    __bf16* __restrict__ out)
{
    int i = (blockIdx.x * 256 + threadIdx.x) * 4;
    float4 a = *(const float4*)(x1 + i);
    float4 b = *(const float4*)(x3 + i);
    bf16x4 o;
    o[0] = (__bf16)(a.x * (b.x / (1.f + __expf(-b.x))));
    o[1] = (__bf16)(a.y * (b.y / (1.f + __expf(-b.y))));
    o[2] = (__bf16)(a.z * (b.z / (1.f + __expf(-b.z))));
    o[3] = (__bf16)(a.w * (b.w / (1.f + __expf(-b.w))));
    *(bf16x4*)(out + i) = o;
}

// ---------------- launch -------------------------------------------------
extern "C" void kernel_launch(void* const* d_in, const int* in_sizes, int n_in,
                              void* d_out, int out_size, void* d_ws, size_t ws_size,
                              hipStream_t stream)
{
    const float* x   = (const float*)d_in[0];
    const float* wq  = (const float*)d_in[1];
    // d_in[2]=wk, d_in[3]=wv: structurally dead (attention uses only past_k/v)
    const float* wo  = (const float*)d_in[4];
    const float* w1  = (const float*)d_in[5];
    const float* w2  = (const float*)d_in[6];
    const float* w3  = (const float*)d_in[7];
    const float* anw = (const float*)d_in[8];
    const float* fnw = (const float*)d_in[9];
    const float* pk  = (const float*)d_in[10];
    const float* pv  = (const float*)d_in[11];
    float* out = (float*)d_out;

    // Workspace live ranges (MB offsets), peak ~126.5 MB:
    //  tab [0,0.5) | h_bf/xq_bf [1,9) | qp [9,73) ; ao_bf [9,17) after qp dies
    //  op [17,81) | xo [1,17) | hf_bf [96,104) | x1 [1,47) | x3 [47,92.1)
    //  g_bf [104,126.5) | w2p [1,65)
    char* ws = (char*)d_ws;
    constexpr size_t MB = 1ull << 20;
    float*  tab   = (float*)(ws);
    __bf16* h_bf  = (__bf16*)(ws + 1 * MB);
    float*  qp    = (float*)(ws + 9 * MB);     // 4 x 16 MB partials
    __bf16* xq_bf = (__bf16*)(ws + 1 * MB);    // alias h_bf (dead)
    __bf16* ao_bf = (__bf16*)(ws + 9 * MB);    // alias qp (dead)
    float*  op    = (float*)(ws + 17 * MB);    // 4 x 16 MB partials
    float*  xo    = (float*)(ws + 1 * MB);     // xq/ao dead by combine
    __bf16* hf_bf = (__bf16*)(ws + 96 * MB);
    float*  x1    = (float*)(ws + 1 * MB);     // 45.1 MB
    float*  x3    = (float*)(ws + 47 * MB);    // 45.1 MB
    __bf16* g_bf  = (__bf16*)(ws + 104 * MB);  // 22.5 MB
    float*  w2p   = (float*)(ws + 1 * MB);     // 4 x 16 MB partials

    rope_table<<<256, 256, 0, stream>>>(tab);
    rmsnorm_bf16<<<SEQLEN, 256, 0, stream>>>(x, anw, h_bf);
    gemm3<4><<<dim3((HIDDEN / 128) * (SEQLEN / 128), 4), 256, 0, stream>>>(
        h_bf, wq, qp, SEQLEN, HIDDEN, HIDDEN);
    combine_rope4<<<SEQLEN, 256, 0, stream>>>(qp, tab, xq_bf);
    attn_flash<<<dim3(SEQLEN / 64, NHEADS), 256, 0, stream>>>(xq_bf, pk, pv, ao_bf);
    gemm3<4><<<dim3((HIDDEN / 128) * (SEQLEN / 128), 4), 256, 0, stream>>>(
        ao_bf, wo, op, SEQLEN, HIDDEN, HIDDEN);
    combine_add4<<<(SEQLEN * HIDDEN) / 1024, 256, 0, stream>>>(op, xo, SEQLEN * HIDDEN);
    rmsnorm_bf16<<<SEQLEN, 256, 0, stream>>>(xo, fnw, hf_bf);
    gemm3<1><<<dim3((FFN / 128) * (SEQLEN / 128), 1), 256, 0, stream>>>(
        hf_bf, w1, x1, SEQLEN, FFN, HIDDEN);
    gemm3<1><<<dim3((FFN / 128) * (SEQLEN / 128), 1), 256, 0, stream>>>(
        hf_bf, w3, x3, SEQLEN, FFN, HIDDEN);
    silu_mul_bf16<<<(SEQLEN * FFN) / 1024, 256, 0, stream>>>(x1, x3, g_bf);
    gemm3<4><<<dim3((HIDDEN / 128) * (SEQLEN / 128), 4), 256, 0, stream>>>(
        g_bf, w2, w2p, SEQLEN, HIDDEN, FFN);
    combine_add4<<<(SEQLEN * HIDDEN) / 1024, 256, 0, stream>>>(w2p, out, SEQLEN * HIDDEN);
}